// Round 2
// baseline (212.046 us; speedup 1.0000x reference)
//
#include <hip/hip_runtime.h>
#include <hip/hip_fp16.h>

typedef _Float16 half8 __attribute__((ext_vector_type(8)));
typedef _Float16 half4v __attribute__((ext_vector_type(4)));
typedef float floatx4 __attribute__((ext_vector_type(4)));

#define HW 128
#define IMG (HW * HW)
#define PH 130          // padded height/width
#define WP 200          // conv_c64 wbuf o-pitch (100 dwords == 4 mod 32)

// async global->LDS, 16 B/lane: LDS dest = wave-uniform base + lane*16.
typedef __attribute__((address_space(3))) _Float16 lds_f16;
typedef __attribute__((address_space(1))) const _Float16 glb_f16;
__device__ __forceinline__ void gload16(const _Float16* g, _Float16* l) {
    __builtin_amdgcn_global_load_lds((glb_f16*)g, (lds_f16*)l, 16, 0, 0);
}

// ---------------------------------------------------------------------------
// pack all weights in ONE dispatch: w[O][C][3][3] f32 -> wp[O][9][C] f16
// ---------------------------------------------------------------------------
__global__ void pack_w_all(const float* __restrict__ w0, const float* __restrict__ w1,
                           const float* __restrict__ w2, const float* __restrict__ wl,
                           _Float16* __restrict__ p0, _Float16* __restrict__ p1,
                           _Float16* __restrict__ p2, _Float16* __restrict__ pl) {
    int idx = blockIdx.x * 256 + threadIdx.x;
    const float* w; _Float16* p; int C; int local;
    if (idx < 92160)       { w = w0; p = p0; C = 160; local = idx; }
    else if (idx < 129024) { w = w1; p = p1; C = 64;  local = idx - 92160; }
    else if (idx < 165888) { w = w2; p = p2; C = 64;  local = idx - 129024; }
    else if (idx < 331776) { w = wl; p = pl; C = 64;  local = idx - 165888; }
    else return;
    int o = local / (C * 9);
    int rem = local % (C * 9);
    int c = rem / 9;
    int t = rem % 9;
    p[(o * 9 + t) * C + c] = (_Float16)w[local];
}

// ---------------------------------------------------------------------------
// zero 1-px halo of padded NHWC tensors
// ---------------------------------------------------------------------------
__device__ __forceinline__ void zero_halo(_Float16* P, int C, int id) {
    int nvec = C / 8;
    int b = id / (516 * nvec);
    int r = id % (516 * nvec);
    int cell = r / nvec;
    int v = r % nvec;
    int hh, ww;
    if (cell < 130)      { hh = 0;   ww = cell; }
    else if (cell < 260) { hh = 129; ww = cell - 130; }
    else if (cell < 388) { hh = cell - 260 + 1; ww = 0; }
    else                 { hh = cell - 388 + 1; ww = 129; }
    half8 z8 = {};
    *reinterpret_cast<half8*>(P + (((size_t)b * PH + hh) * PH + ww) * C + v * 8) = z8;
}

__global__ void zero_pads_pre(_Float16* __restrict__ X0, _Float16* __restrict__ Q1) {
    int id = blockIdx.x * 256 + threadIdx.x;     // 82560 + 33024
    if (id < 82560) zero_halo(X0, 160, id);
    else if (id < 115584) zero_halo(Q1, 64, id - 82560);
}

__global__ void zero_pads64(_Float16* __restrict__ P) {
    int id = blockIdx.x * 256 + threadIdx.x;
    if (id < 33024) zero_halo(P, 64, id);
}

// ---------------------------------------------------------------------------
// pack input -> X0 padded NHWC f16 [b][130][130][160] (interior)
// ---------------------------------------------------------------------------
__global__ __launch_bounds__(256)
void pack_in(const float* __restrict__ z, const float* __restrict__ bb,
             const float* __restrict__ ms, const float* __restrict__ mu,
             _Float16* __restrict__ X0) {
    __shared__ _Float16 lds[160 * 132];
    int b = blockIdx.x >> 7;
    int h = blockIdx.x & 127;
    int tid = threadIdx.x;

    for (int i = 0; i < 20; i++) {
        int id = i * 256 + tid;
        int c = id >> 5;
        int col = (id & 31) * 4;
        const float* src; int cs; int csz;
        if (c < 64)       { src = bb; cs = c;       csz = 64; }
        else if (c < 96)  { src = z;  cs = c - 64;  csz = 32; }
        else if (c < 128) { src = ms; cs = c - 96;  csz = 32; }
        else              { src = mu; cs = c - 128; csz = 32; }
        float4 v = *reinterpret_cast<const float4*>(
            src + ((size_t)b * csz + cs) * IMG + h * HW + col);
        half4v hv = { (_Float16)v.x, (_Float16)v.y, (_Float16)v.z, (_Float16)v.w };
        *reinterpret_cast<half4v*>(&lds[c * 132 + col]) = hv;
    }
    __syncthreads();
    _Float16* dst = X0 + (((size_t)b * PH + (h + 1)) * PH + 1) * 160;
    for (int i = 0; i < 10; i++) {
        int id = i * 256 + tid;
        int pix = id / 20;
        int c0 = (id % 20) * 8;
        half8 hv;
        #pragma unroll
        for (int e = 0; e < 8; e++) hv[e] = lds[(c0 + e) * 132 + pix];
        *reinterpret_cast<half8*>(dst + (size_t)pix * 160 + c0) = hv;
    }
}

// ---------------------------------------------------------------------------
// conv0: CIN=160. v13: half-row blocks (64 px computed, 66 staged) with
// DOUBLE-BUFFERED X staging + dw-sliced ping-pong weight register prefetch.
// grid 2048 (b, h, w-half). Per-r: stage row r+1 into the idle xs buffer is
// issued BEFORE compute on row r, so its L3 latency hides under the MFMAs
// and the compiler's vmcnt(0)-before-barrier drain lands after compute.
// LDS 2 x 66 x 168 x 2B = 44352 -> 3 blocks/CU; rounds (3,3,2) vs old (3,1).
// ---------------------------------------------------------------------------
__global__ __launch_bounds__(256, 3)
void conv3_c160(const _Float16* __restrict__ X, const _Float16* __restrict__ Wp,
                const float* __restrict__ bias, _Float16* __restrict__ Y) {
    __shared__ _Float16 xs[2][66 * 168];   // 44352 B
    int blk = blockIdx.x;
    int b = blk >> 8;
    int h = (blk >> 1) & 127;
    int wb64 = (blk & 1) * 64;
    int tid = threadIdx.x;
    int lane = tid & 63;
    int wave = tid >> 6;
    int ph = wave & 1;
    int oh = wave >> 1;
    int l15 = lane & 15;
    int l4  = lane >> 4;

    floatx4 acc[2][2] = {};
    half8 SA[10], SB[10];   // ping-pong weight slices: 10 half8 = 40 VGPR each

    // per-lane weight base: addr(k,cb,n) = wl + n*23040 + k*160 + cb*32
    const _Float16* wl = Wp + (size_t)((oh * 32 + l15) * 9) * 160 + l4 * 8;

#define LOADW(S, k) { \
    _Pragma("unroll") \
    for (int cb = 0; cb < 5; cb++) \
      _Pragma("unroll") \
      for (int n = 0; n < 2; n++) \
        S[cb * 2 + n] = *reinterpret_cast<const half8*>( \
            wl + n * 23040 + (k) * 160 + cb * 32); }

#define STAGE160(BUF, r) { \
    const _Float16* grow = X + (((size_t)b * PH + (h + (r))) * PH + wb64) * 160; \
    _Pragma("unroll") \
    for (int i = 0; i < 6; i++) { \
      int id = i * 256 + tid; \
      if (id < 1320) { \
        half8 v = *reinterpret_cast<const half8*>(grow + (size_t)id * 8); \
        *reinterpret_cast<half8*>(&BUF[(id / 20) * 168 + (id % 20) * 8]) = v; \
      } } }

#define COMP160(dw, S, BUF) { \
    _Pragma("unroll") \
    for (int cb = 0; cb < 5; cb++) { \
      int kofs = cb * 32 + l4 * 8; \
      half8 af[2]; \
      _Pragma("unroll") \
      for (int m = 0; m < 2; m++) { \
        int p = ph * 32 + m * 16 + l15; \
        af[m] = *reinterpret_cast<const half8*>(&BUF[(p + (dw)) * 168 + kofs]); \
      } \
      _Pragma("unroll") \
      for (int m = 0; m < 2; m++) \
        _Pragma("unroll") \
        for (int n = 0; n < 2; n++) \
          acc[m][n] = __builtin_amdgcn_mfma_f32_16x16x32_f16( \
              af[m], S[cb * 2 + n], acc[m][n], 0, 0, 0); } }

    // ---- stage s = r*3+dw; SA/SB weight ping-pong, X double-buffer ----
    LOADW(SA, 0);
    STAGE160(xs[0], 0);
    __syncthreads();                 // buf0 (r=0) ready
    STAGE160(xs[1], 1);              // prefetch r=1 under compute of r=0
    LOADW(SB, 1);  COMP160(0, SA, xs[0]);
    LOADW(SA, 2);  COMP160(1, SB, xs[0]);
    LOADW(SB, 3);  COMP160(2, SA, xs[0]);
    __syncthreads();                 // buf1 (r=1) ready; buf0 reads done
    STAGE160(xs[0], 2);              // prefetch r=2 under compute of r=1
    LOADW(SA, 4);  COMP160(0, SB, xs[1]);
    LOADW(SB, 5);  COMP160(1, SA, xs[1]);
    LOADW(SA, 6);  COMP160(2, SB, xs[1]);
    __syncthreads();                 // buf0 (r=2) ready
    LOADW(SB, 7);  COMP160(0, SA, xs[0]);
    LOADW(SA, 8);  COMP160(1, SB, xs[0]);
    COMP160(2, SA, xs[0]);

#undef LOADW
#undef STAGE160
#undef COMP160

    _Float16* dst = Y + (((size_t)b * PH + (h + 1)) * PH + 1 + wb64) * 64;
    #pragma unroll
    for (int m = 0; m < 2; m++)
        #pragma unroll
        for (int n = 0; n < 2; n++) {
            int o = oh * 32 + n * 16 + l15;
            float bv = bias[o];
            #pragma unroll
            for (int q = 0; q < 4; q++) {
                int pix = ph * 32 + m * 16 + l4 * 4 + q;
                float v = acc[m][n][q] + bv;
                v = v > 0.f ? v : 0.01f * v;
                dst[(size_t)pix * 64 + o] = (_Float16)v;
            }
        }
}

// ---------------------------------------------------------------------------
// conv_c64: CIN=64, v10 form (known-good): all-LDS inner loop, WP=200 pitch.
// ---------------------------------------------------------------------------
__global__ __launch_bounds__(256, 3)
void conv3_c64(const _Float16* __restrict__ X, const _Float16* __restrict__ Wp,
               const float* __restrict__ bias, _Float16* __restrict__ Y) {
    __shared__ _Float16 smem[9360 + 64 * WP];
    _Float16* xs = smem;            // [130][72]
    _Float16* wbuf = smem + 9360;   // [64][WP]
    int b = blockIdx.x >> 7;
    int h = blockIdx.x & 127;
    int tid = threadIdx.x;
    int lane = tid & 63;
    int wave = tid >> 6;
    int ph = wave & 1;
    int oh = wave >> 1;
    int l15 = lane & 15;
    int l4  = lane >> 4;

    floatx4 acc[4][2] = {};
    const _Float16* xbase = X + ((size_t)b * PH + h) * (PH * 64);

    for (int r = 0; r < 3; r++) {
        if (r) __syncthreads();
        for (int i = 0; i < 5; i++) {
            int id = i * 256 + tid;
            if (id < 1040) {
                half8 v = *reinterpret_cast<const half8*>(
                    xbase + (size_t)r * (PH * 64) + (size_t)id * 8);
                *reinterpret_cast<half8*>(&xs[(id >> 3) * 72 + (id & 7) * 8]) = v;
            }
        }
        for (int i = 0; i < 6; i++) {
            int id = i * 256 + tid;
            int o = id / 24, j = id % 24;
            half8 v = *reinterpret_cast<const half8*>(
                Wp + ((size_t)o * 9 + r * 3) * 64 + j * 8);
            *reinterpret_cast<half8*>(&wbuf[o * WP + j * 8]) = v;
        }
        __syncthreads();
        #pragma unroll
        for (int dw = 0; dw < 3; dw++)
            #pragma unroll
            for (int cb = 0; cb < 2; cb++) {
                int kofs = cb * 32 + l4 * 8;
                half8 bf[2];
                #pragma unroll
                for (int n = 0; n < 2; n++) {
                    int o = oh * 32 + n * 16 + l15;
                    bf[n] = *reinterpret_cast<const half8*>(
                        &wbuf[o * WP + dw * 64 + kofs]);
                }
                half8 af[4];
                #pragma unroll
                for (int m = 0; m < 4; m++) {
                    int p = ph * 64 + m * 16 + l15;
                    af[m] = *reinterpret_cast<const half8*>(&xs[(p + dw) * 72 + kofs]);
                }
                #pragma unroll
                for (int m = 0; m < 4; m++)
                    #pragma unroll
                    for (int n = 0; n < 2; n++)
                        acc[m][n] = __builtin_amdgcn_mfma_f32_16x16x32_f16(
                            af[m], bf[n], acc[m][n], 0, 0, 0);
            }
    }
    _Float16* dst = Y + (((size_t)b * PH + (h + 1)) * PH + 1) * 64;
    #pragma unroll
    for (int m = 0; m < 4; m++)
        #pragma unroll
        for (int n = 0; n < 2; n++) {
            int o = oh * 32 + n * 16 + l15;
            float bv = bias[o];
            #pragma unroll
            for (int q = 0; q < 4; q++) {
                int pix = ph * 64 + m * 16 + l4 * 4 + q;
                float v = acc[m][n][q] + bv;
                v = v > 0.f ? v : 0.01f * v;
                dst[(size_t)pix * 64 + o] = (_Float16)v;
            }
        }
}

// ---------------------------------------------------------------------------
// head_gemm: pure GEMM, logits -> global f16 [bi][h][288 od][128 px].
// block = row x 96 outs, 256 thr = 4 waves (2 pxh x 2 og), wave 4M x 3N.
// LDS 53504 B -> 3 blocks/CU. conflict-free gload_lds + XOR-swizzle staging.
// ---------------------------------------------------------------------------
__global__ __launch_bounds__(256, 3)
void head_gemm(const _Float16* __restrict__ X, const _Float16* __restrict__ Wp,
               const float* __restrict__ b_last, _Float16* __restrict__ Lg,
               int bbase) {
    __shared__ _Float16 smem[26752];      // 53504 B
    _Float16* xs = smem;                  // [130][8] half8 linear
    _Float16* wbuf = smem + 8320;         // [96][24] half8 linear
    _Float16* tb = smem;                  // [96][132] transpose buf (overlay)
    int blk = blockIdx.x;
    int ct = blk >> 9;          // 0..2 out-third
    int bi = (blk >> 7) & 3;    // local batch 0..3
    int h  = blk & 127;
    int b = bbase + bi;
    int tid = threadIdx.x;
    int lane = tid & 63;
    int wave = tid >> 6;
    int pxh = wave & 1;
    int og  = wave >> 1;        // 0..1
    int l15 = lane & 15;
    int l4  = lane >> 4;

    floatx4 acc[4][3] = {};
    const _Float16* xbase = X + ((size_t)b * PH + h) * (PH * 64);
    const _Float16* wbase = Wp + (size_t)ct * 96 * 9 * 64;

    for (int r = 0; r < 3; r++) {
        if (r) __syncthreads();
        const _Float16* xrow = xbase + (size_t)r * (PH * 64);
        for (int i = 0; i < 5; i++) {
            int sbase = i * 256 + wave * 64;
            int s = sbase + lane;
            if (s < 1040) {
                int px = s >> 3;
                int j = (s & 7) ^ (px & 7);
                gload16(xrow + (size_t)(px * 8 + j) * 8, xs + (size_t)sbase * 8);
            }
        }
        const _Float16* wrow = wbase + r * 192;
        for (int i = 0; i < 9; i++) {
            int tbs = i * 256 + wave * 64;
            int t = tbs + lane;           // < 2304 always
            int o = t / 24, ks = t % 24;
            int k = (ks & 0x18) | ((ks & 7) ^ (o & 7));
            gload16(wrow + (size_t)(o * 576 + k * 8), wbuf + (size_t)tbs * 8);
        }
        __syncthreads();
        #pragma unroll
        for (int dw = 0; dw < 3; dw++)
            #pragma unroll
            for (int cb = 0; cb < 2; cb++) {
                int kb = dw * 8 + cb * 4 + l4;
                half8 bf[3];
                #pragma unroll
                for (int n = 0; n < 3; n++) {
                    int ol = og * 48 + n * 16 + l15;
                    int ksw = (kb & 0x18) | ((kb & 7) ^ (ol & 7));
                    bf[n] = *reinterpret_cast<const half8*>(&wbuf[ol * 192 + ksw * 8]);
                }
                int j = cb * 4 + l4;
                half8 af[4];
                #pragma unroll
                for (int m = 0; m < 4; m++) {
                    int px = pxh * 64 + m * 16 + l15 + dw;
                    af[m] = *reinterpret_cast<const half8*>(
                        &xs[px * 64 + (j ^ (px & 7)) * 8]);
                }
                #pragma unroll
                for (int m = 0; m < 4; m++)
                    #pragma unroll
                    for (int n = 0; n < 3; n++)
                        acc[m][n] = __builtin_amdgcn_mfma_f32_16x16x32_f16(
                            af[m], bf[n], acc[m][n], 0, 0, 0);
            }
    }
    __syncthreads();    // xs/wbuf dead; tb overlays

    // logits (bias added) -> tb [od 0..95][132 px pitch]
    #pragma unroll
    for (int m = 0; m < 4; m++)
        #pragma unroll
        for (int n = 0; n < 3; n++) {
            int od = og * 48 + n * 16 + l15;
            float bv = b_last[ct * 96 + od];
            half4v hv;
            #pragma unroll
            for (int q = 0; q < 4; q++) hv[q] = (_Float16)(acc[m][n][q] + bv);
            *reinterpret_cast<half4v*>(&tb[od * 132 + pxh * 64 + m * 16 + l4 * 4]) = hv;
        }
    __syncthreads();

    // tb -> global, coalesced half8 rows
    _Float16* dst = Lg + (((size_t)bi * 128 + h) * 288 + (size_t)ct * 96) * 128;
    #pragma unroll
    for (int i = 0; i < 6; i++) {
        int id = i * 256 + tid;           // 0..1535
        int od = id >> 4;
        int sl = id & 15;
        half8 v = *reinterpret_cast<const half8*>(&tb[od * 132 + sl * 8]);
        *reinterpret_cast<half8*>(dst + (size_t)od * 128 + sl * 8) = v;
    }
}

// ---------------------------------------------------------------------------
// fuse_sm: barrier-free streaming softmax + combine. One thread per
// output pixel. All loads coalesced; full-occupancy latency hiding.
// ---------------------------------------------------------------------------
__global__ __launch_bounds__(256)
void fuse_sm(const _Float16* __restrict__ Lg, const float* __restrict__ ms,
             const float* __restrict__ zin, float* __restrict__ out, int bbase) {
    int blk = blockIdx.x;
    int bi = blk >> 11;
    int c  = (blk >> 6) & 31;
    int hp = blk & 63;
    int tid = threadIdx.x;
    int h = hp * 2 + (tid >> 7);
    int w = tid & 127;
    int b = bbase + bi;

    const _Float16* lrow = Lg + (((size_t)bi * 128 + h) * 288 + (size_t)c * 9) * 128 + w;
    float L[9];
    float mx = 0.f;                      // implicit zero logit
    #pragma unroll
    for (int j = 0; j < 9; j++) { L[j] = (float)lrow[j * 128]; mx = fmaxf(mx, L[j]); }
    float ez = __expf(-mx);
    float sum = ez;
    float e[9];
    #pragma unroll
    for (int j = 0; j < 9; j++) { e[j] = __expf(L[j] - mx); sum += e[j]; }
    float inv = 1.f / sum;
    const float* msb = ms + ((size_t)b * 32 + c) * IMG;
    float accv = ez * inv * zin[((size_t)b * 32 + c) * IMG + h * HW + w];
    #pragma unroll
    for (int kh = 0; kh < 3; kh++) {
        int h2 = h + kh - 1;
        int h2c = min(max(h2, 0), 127);
        bool okh = (unsigned)h2 < 128u;
        #pragma unroll
        for (int kw = 0; kw < 3; kw++) {
            int w2 = w + kw - 1;
            int w2c = min(max(w2, 0), 127);
            bool okw = (unsigned)w2 < 128u;
            float mv = msb[h2c * HW + w2c];
            accv += e[kh * 3 + kw] * inv * ((okh && okw) ? mv : 0.f);
        }
    }
    out[((size_t)b * 32 + c) * IMG + h * HW + w] = accv;
}

// ---------------------------------------------------------------------------
extern "C" void kernel_launch(void* const* d_in, const int* in_sizes, int n_in,
                              void* d_out, int out_size, void* d_ws, size_t ws_size,
                              hipStream_t stream) {
    const float* z  = (const float*)d_in[0];
    const float* bb = (const float*)d_in[1];
    const float* ms = (const float*)d_in[2];
    const float* mu = (const float*)d_in[3];
    const float* w0 = (const float*)d_in[4];
    const float* b0 = (const float*)d_in[5];
    const float* w1 = (const float*)d_in[6];
    const float* b1 = (const float*)d_in[7];
    const float* w2 = (const float*)d_in[8];
    const float* b2 = (const float*)d_in[9];
    const float* wl = (const float*)d_in[10];
    const float* bl = (const float*)d_in[11];

    char* ws = (char*)d_ws;
    _Float16* Wp0 = (_Float16*)(ws + 0);          // 184320
    _Float16* Wp1 = (_Float16*)(ws + 184320);     // 73728
    _Float16* Wp2 = (_Float16*)(ws + 258048);     // 73728
    _Float16* WpL = (_Float16*)(ws + 331776);     // 331776
    _Float16* BufA = (_Float16*)(ws + 663552);    // 43,264,000  (160ch padded)
    _Float16* BufB = (_Float16*)(ws + 43927552);  // 17,305,600  (64ch padded)

    _Float16* X0 = BufA;
    _Float16* Q1 = BufB;
    _Float16* Q2 = BufA;   // overlays X0 (dead after conv0)
    _Float16* Q3 = BufB;   // overlays Q1 (same layout -> halo stays zero)
    _Float16* Lg = BufA;   // logits slab (BufA dead after conv2)

    pack_w_all<<<(331776 + 255) / 256, 256, 0, stream>>>(w0, w1, w2, wl, Wp0, Wp1, Wp2, WpL);
    zero_pads_pre<<<(115584 + 255) / 256, 256, 0, stream>>>(X0, Q1);
    pack_in<<<1024, 256, 0, stream>>>(z, bb, ms, mu, X0);

    conv3_c160<<<2048, 256, 0, stream>>>(X0, Wp0, b0, Q1);
    zero_pads64<<<(33024 + 255) / 256, 256, 0, stream>>>(Q2);
    conv3_c64<<<1024, 256, 0, stream>>>(Q1, Wp1, b1, Q2);
    conv3_c64<<<1024, 256, 0, stream>>>(Q2, Wp2, b2, Q3);

    head_gemm<<<1536, 256, 0, stream>>>(Q3, WpL, bl, Lg, 0);
    fuse_sm<<<8192, 256, 0, stream>>>(Lg, ms, z, (float*)d_out, 0);
    head_gemm<<<1536, 256, 0, stream>>>(Q3, WpL, bl, Lg, 4);
    fuse_sm<<<8192, 256, 0, stream>>>(Lg, ms, z, (float*)d_out, 4);
}

// Round 3
// 189.148 us; speedup vs baseline: 1.1211x; 1.1211x over previous
//
#include <hip/hip_runtime.h>
#include <hip/hip_fp16.h>

typedef _Float16 half8 __attribute__((ext_vector_type(8)));
typedef _Float16 half4v __attribute__((ext_vector_type(4)));
typedef float floatx4 __attribute__((ext_vector_type(4)));

#define HW 128
#define IMG (HW * HW)
#define PH 130          // padded height/width
#define WP 200          // conv_c64 wbuf o-pitch (100 dwords == 4 mod 32)

// async global->LDS, 16 B/lane: LDS dest = wave-uniform base + lane*16.
typedef __attribute__((address_space(3))) _Float16 lds_f16;
typedef __attribute__((address_space(1))) const _Float16 glb_f16;
__device__ __forceinline__ void gload16(const _Float16* g, _Float16* l) {
    __builtin_amdgcn_global_load_lds((glb_f16*)g, (lds_f16*)l, 16, 0, 0);
}

// ---------------------------------------------------------------------------
// pack all weights in ONE dispatch.
// w1/w2/wl: w[O][C][3][3] f32 -> wp[O][9][C] f16  (LDS-staged in consumers)
// w0:       w[O][160][3][3] f32 -> FRAGMENT-ORDER f16:
//           W0f[oh][frag=(t*5+cb)*2+n][lane=l4*16+l15][8e]
//           (o = oh*32+n*16+l15, c = cb*32+l4*8+e, tap t)
//           => conv3_c160's per-wave weight-slice load is 64 lanes x 16 B
//           CONTIGUOUS (1 KB): 16 cache lines vs 32, no address divergence.
// ---------------------------------------------------------------------------
__global__ void pack_w_all(const float* __restrict__ w0, const float* __restrict__ w1,
                           const float* __restrict__ w2, const float* __restrict__ wl,
                           _Float16* __restrict__ p0, _Float16* __restrict__ p1,
                           _Float16* __restrict__ p2, _Float16* __restrict__ pl) {
    int idx = blockIdx.x * 256 + threadIdx.x;
    if (idx < 92160) {
        int local = idx;
        int o = local / 1440;          // 160*9
        int rem = local % 1440;
        int c = rem / 9;
        int t = rem % 9;
        int oh = o >> 5, n = (o >> 4) & 1, l15 = o & 15;
        int cb = c >> 5, l4 = (c >> 3) & 3, e = c & 7;
        int frag = (t * 5 + cb) * 2 + n;
        p0[(size_t)oh * 46080 + frag * 512 + (l4 * 16 + l15) * 8 + e] =
            (_Float16)w0[local];
        return;
    }
    const float* w; _Float16* p; int C; int local;
    if (idx < 129024)      { w = w1; p = p1; C = 64;  local = idx - 92160; }
    else if (idx < 165888) { w = w2; p = p2; C = 64;  local = idx - 129024; }
    else if (idx < 331776) { w = wl; p = pl; C = 64;  local = idx - 165888; }
    else return;
    int o = local / (C * 9);
    int rem = local % (C * 9);
    int c = rem / 9;
    int t = rem % 9;
    p[(o * 9 + t) * C + c] = (_Float16)w[local];
}

// ---------------------------------------------------------------------------
// zero 1-px halo of padded NHWC tensors
// ---------------------------------------------------------------------------
__device__ __forceinline__ void zero_halo(_Float16* P, int C, int id) {
    int nvec = C / 8;
    int b = id / (516 * nvec);
    int r = id % (516 * nvec);
    int cell = r / nvec;
    int v = r % nvec;
    int hh, ww;
    if (cell < 130)      { hh = 0;   ww = cell; }
    else if (cell < 260) { hh = 129; ww = cell - 130; }
    else if (cell < 388) { hh = cell - 260 + 1; ww = 0; }
    else                 { hh = cell - 388 + 1; ww = 129; }
    half8 z8 = {};
    *reinterpret_cast<half8*>(P + (((size_t)b * PH + hh) * PH + ww) * C + v * 8) = z8;
}

__global__ void zero_pads_pre(_Float16* __restrict__ X0, _Float16* __restrict__ Q1) {
    int id = blockIdx.x * 256 + threadIdx.x;     // 82560 + 33024
    if (id < 82560) zero_halo(X0, 160, id);
    else if (id < 115584) zero_halo(Q1, 64, id - 82560);
}

__global__ void zero_pads64(_Float16* __restrict__ P) {
    int id = blockIdx.x * 256 + threadIdx.x;
    if (id < 33024) zero_halo(P, 64, id);
}

// ---------------------------------------------------------------------------
// pack input -> X0 padded NHWC f16 [b][130][130][160] (interior)
// ---------------------------------------------------------------------------
__global__ __launch_bounds__(256)
void pack_in(const float* __restrict__ z, const float* __restrict__ bb,
             const float* __restrict__ ms, const float* __restrict__ mu,
             _Float16* __restrict__ X0) {
    __shared__ _Float16 lds[160 * 132];
    int b = blockIdx.x >> 7;
    int h = blockIdx.x & 127;
    int tid = threadIdx.x;

    for (int i = 0; i < 20; i++) {
        int id = i * 256 + tid;
        int c = id >> 5;
        int col = (id & 31) * 4;
        const float* src; int cs; int csz;
        if (c < 64)       { src = bb; cs = c;       csz = 64; }
        else if (c < 96)  { src = z;  cs = c - 64;  csz = 32; }
        else if (c < 128) { src = ms; cs = c - 96;  csz = 32; }
        else              { src = mu; cs = c - 128; csz = 32; }
        float4 v = *reinterpret_cast<const float4*>(
            src + ((size_t)b * csz + cs) * IMG + h * HW + col);
        half4v hv = { (_Float16)v.x, (_Float16)v.y, (_Float16)v.z, (_Float16)v.w };
        *reinterpret_cast<half4v*>(&lds[c * 132 + col]) = hv;
    }
    __syncthreads();
    _Float16* dst = X0 + (((size_t)b * PH + (h + 1)) * PH + 1) * 160;
    for (int i = 0; i < 10; i++) {
        int id = i * 256 + tid;
        int pix = id / 20;
        int c0 = (id % 20) * 8;
        half8 hv;
        #pragma unroll
        for (int e = 0; e < 8; e++) hv[e] = lds[(c0 + e) * 132 + pix];
        *reinterpret_cast<half8*>(dst + (size_t)pix * 160 + c0) = hv;
    }
}

// ---------------------------------------------------------------------------
// conv0: CIN=160. v14: round-1 structure (full-row blocks, grid 1024,
// dw-sliced ping-pong weight prefetch) + FRAGMENT-ORDERED weight layout:
// each LOADW slice is a coalesced 1 KB wave load (was 2880-B-strided,
// 32 lines + address divergence per load -> the dominant per-block cost).
// ---------------------------------------------------------------------------
__global__ __launch_bounds__(256, 2)
void conv3_c160(const _Float16* __restrict__ X, const _Float16* __restrict__ Wp,
                const float* __restrict__ bias, _Float16* __restrict__ Y) {
    __shared__ _Float16 xs[130 * 168];   // 43680 B
    int b = blockIdx.x >> 7;
    int h = blockIdx.x & 127;
    int tid = threadIdx.x;
    int lane = tid & 63;
    int wave = tid >> 6;
    int ph = wave & 1;
    int oh = wave >> 1;
    int l15 = lane & 15;
    int l4  = lane >> 4;

    floatx4 acc[4][2] = {};
    half8 SA[10], SB[10];   // ping-pong weight slices: 10 half8 = 40 VGPR each

    // fragment-ordered weights: W0f[oh][frag][lane][8]; frag = (k*5+cb)*2+n
    const _Float16* wl = Wp + (size_t)oh * 46080 + lane * 8;

#define LOADW(S, k) { \
    _Pragma("unroll") \
    for (int cb = 0; cb < 5; cb++) \
      _Pragma("unroll") \
      for (int n = 0; n < 2; n++) \
        S[cb * 2 + n] = *reinterpret_cast<const half8*>( \
            wl + (size_t)(((k) * 5 + cb) * 2 + n) * 512); }

#define STAGE160(r) { \
    const _Float16* grow = X + ((size_t)b * PH + (h + (r))) * PH * 160; \
    _Pragma("unroll") \
    for (int i = 0; i < 11; i++) { \
      int id = i * 256 + tid; \
      if (id < 2600) { \
        half8 v = *reinterpret_cast<const half8*>(grow + (size_t)id * 8); \
        *reinterpret_cast<half8*>(&xs[(id / 20) * 168 + (id % 20) * 8]) = v; \
      } } }

#define COMP160(dw, S) { \
    _Pragma("unroll") \
    for (int cb = 0; cb < 5; cb++) { \
      int kofs = cb * 32 + l4 * 8; \
      half8 af[4]; \
      _Pragma("unroll") \
      for (int m = 0; m < 4; m++) { \
        int p = ph * 64 + m * 16 + l15; \
        af[m] = *reinterpret_cast<const half8*>(&xs[(p + (dw)) * 168 + kofs]); \
      } \
      _Pragma("unroll") \
      for (int m = 0; m < 4; m++) \
        _Pragma("unroll") \
        for (int n = 0; n < 2; n++) \
          acc[m][n] = __builtin_amdgcn_mfma_f32_16x16x32_f16( \
              af[m], S[cb * 2 + n], acc[m][n], 0, 0, 0); } }

    // ---- stage k = r*3+dw; ping-pong SA/SB, prefetch distance 1 stage ----
    LOADW(SA, 0);
    STAGE160(0);
    __syncthreads();
    LOADW(SB, 1);  COMP160(0, SA);
    LOADW(SA, 2);  COMP160(1, SB);
    LOADW(SB, 3);  COMP160(2, SA);
    __syncthreads();
    STAGE160(1);
    __syncthreads();
    LOADW(SA, 4);  COMP160(0, SB);
    LOADW(SB, 5);  COMP160(1, SA);
    LOADW(SA, 6);  COMP160(2, SB);
    __syncthreads();
    STAGE160(2);
    __syncthreads();
    LOADW(SB, 7);  COMP160(0, SA);
    LOADW(SA, 8);  COMP160(1, SB);
    COMP160(2, SA);

#undef LOADW
#undef STAGE160
#undef COMP160

    _Float16* dst = Y + (((size_t)b * PH + (h + 1)) * PH + 1) * 64;
    #pragma unroll
    for (int m = 0; m < 4; m++)
        #pragma unroll
        for (int n = 0; n < 2; n++) {
            int o = oh * 32 + n * 16 + l15;
            float bv = bias[o];
            #pragma unroll
            for (int q = 0; q < 4; q++) {
                int pix = ph * 64 + m * 16 + l4 * 4 + q;
                float v = acc[m][n][q] + bv;
                v = v > 0.f ? v : 0.01f * v;
                dst[(size_t)pix * 64 + o] = (_Float16)v;
            }
        }
}

// ---------------------------------------------------------------------------
// conv_c64: CIN=64, v10 form (known-good): all-LDS inner loop, WP=200 pitch.
// ---------------------------------------------------------------------------
__global__ __launch_bounds__(256, 3)
void conv3_c64(const _Float16* __restrict__ X, const _Float16* __restrict__ Wp,
               const float* __restrict__ bias, _Float16* __restrict__ Y) {
    __shared__ _Float16 smem[9360 + 64 * WP];
    _Float16* xs = smem;            // [130][72]
    _Float16* wbuf = smem + 9360;   // [64][WP]
    int b = blockIdx.x >> 7;
    int h = blockIdx.x & 127;
    int tid = threadIdx.x;
    int lane = tid & 63;
    int wave = tid >> 6;
    int ph = wave & 1;
    int oh = wave >> 1;
    int l15 = lane & 15;
    int l4  = lane >> 4;

    floatx4 acc[4][2] = {};
    const _Float16* xbase = X + ((size_t)b * PH + h) * (PH * 64);

    for (int r = 0; r < 3; r++) {
        if (r) __syncthreads();
        for (int i = 0; i < 5; i++) {
            int id = i * 256 + tid;
            if (id < 1040) {
                half8 v = *reinterpret_cast<const half8*>(
                    xbase + (size_t)r * (PH * 64) + (size_t)id * 8);
                *reinterpret_cast<half8*>(&xs[(id >> 3) * 72 + (id & 7) * 8]) = v;
            }
        }
        for (int i = 0; i < 6; i++) {
            int id = i * 256 + tid;
            int o = id / 24, j = id % 24;
            half8 v = *reinterpret_cast<const half8*>(
                Wp + ((size_t)o * 9 + r * 3) * 64 + j * 8);
            *reinterpret_cast<half8*>(&wbuf[o * WP + j * 8]) = v;
        }
        __syncthreads();
        #pragma unroll
        for (int dw = 0; dw < 3; dw++)
            #pragma unroll
            for (int cb = 0; cb < 2; cb++) {
                int kofs = cb * 32 + l4 * 8;
                half8 bf[2];
                #pragma unroll
                for (int n = 0; n < 2; n++) {
                    int o = oh * 32 + n * 16 + l15;
                    bf[n] = *reinterpret_cast<const half8*>(
                        &wbuf[o * WP + dw * 64 + kofs]);
                }
                half8 af[4];
                #pragma unroll
                for (int m = 0; m < 4; m++) {
                    int p = ph * 64 + m * 16 + l15;
                    af[m] = *reinterpret_cast<const half8*>(&xs[(p + dw) * 72 + kofs]);
                }
                #pragma unroll
                for (int m = 0; m < 4; m++)
                    #pragma unroll
                    for (int n = 0; n < 2; n++)
                        acc[m][n] = __builtin_amdgcn_mfma_f32_16x16x32_f16(
                            af[m], bf[n], acc[m][n], 0, 0, 0);
            }
    }
    _Float16* dst = Y + (((size_t)b * PH + (h + 1)) * PH + 1) * 64;
    #pragma unroll
    for (int m = 0; m < 4; m++)
        #pragma unroll
        for (int n = 0; n < 2; n++) {
            int o = oh * 32 + n * 16 + l15;
            float bv = bias[o];
            #pragma unroll
            for (int q = 0; q < 4; q++) {
                int pix = ph * 64 + m * 16 + l4 * 4 + q;
                float v = acc[m][n][q] + bv;
                v = v > 0.f ? v : 0.01f * v;
                dst[(size_t)pix * 64 + o] = (_Float16)v;
            }
        }
}

// ---------------------------------------------------------------------------
// head_gemm: pure GEMM, logits -> global f16 [bi][h][288 od][128 px].
// block = row x 96 outs, 256 thr = 4 waves (2 pxh x 2 og), wave 4M x 3N.
// LDS 53504 B -> 3 blocks/CU. conflict-free gload_lds + XOR-swizzle staging.
// ---------------------------------------------------------------------------
__global__ __launch_bounds__(256, 3)
void head_gemm(const _Float16* __restrict__ X, const _Float16* __restrict__ Wp,
               const float* __restrict__ b_last, _Float16* __restrict__ Lg,
               int bbase) {
    __shared__ _Float16 smem[26752];      // 53504 B
    _Float16* xs = smem;                  // [130][8] half8 linear
    _Float16* wbuf = smem + 8320;         // [96][24] half8 linear
    _Float16* tb = smem;                  // [96][132] transpose buf (overlay)
    int blk = blockIdx.x;
    int ct = blk >> 9;          // 0..2 out-third
    int bi = (blk >> 7) & 3;    // local batch 0..3
    int h  = blk & 127;
    int b = bbase + bi;
    int tid = threadIdx.x;
    int lane = tid & 63;
    int wave = tid >> 6;
    int pxh = wave & 1;
    int og  = wave >> 1;        // 0..1
    int l15 = lane & 15;
    int l4  = lane >> 4;

    floatx4 acc[4][3] = {};
    const _Float16* xbase = X + ((size_t)b * PH + h) * (PH * 64);
    const _Float16* wbase = Wp + (size_t)ct * 96 * 9 * 64;

    for (int r = 0; r < 3; r++) {
        if (r) __syncthreads();
        const _Float16* xrow = xbase + (size_t)r * (PH * 64);
        for (int i = 0; i < 5; i++) {
            int sbase = i * 256 + wave * 64;
            int s = sbase + lane;
            if (s < 1040) {
                int px = s >> 3;
                int j = (s & 7) ^ (px & 7);
                gload16(xrow + (size_t)(px * 8 + j) * 8, xs + (size_t)sbase * 8);
            }
        }
        const _Float16* wrow = wbase + r * 192;
        for (int i = 0; i < 9; i++) {
            int tbs = i * 256 + wave * 64;
            int t = tbs + lane;           // < 2304 always
            int o = t / 24, ks = t % 24;
            int k = (ks & 0x18) | ((ks & 7) ^ (o & 7));
            gload16(wrow + (size_t)(o * 576 + k * 8), wbuf + (size_t)tbs * 8);
        }
        __syncthreads();
        #pragma unroll
        for (int dw = 0; dw < 3; dw++)
            #pragma unroll
            for (int cb = 0; cb < 2; cb++) {
                int kb = dw * 8 + cb * 4 + l4;
                half8 bf[3];
                #pragma unroll
                for (int n = 0; n < 3; n++) {
                    int ol = og * 48 + n * 16 + l15;
                    int ksw = (kb & 0x18) | ((kb & 7) ^ (ol & 7));
                    bf[n] = *reinterpret_cast<const half8*>(&wbuf[ol * 192 + ksw * 8]);
                }
                int j = cb * 4 + l4;
                half8 af[4];
                #pragma unroll
                for (int m = 0; m < 4; m++) {
                    int px = pxh * 64 + m * 16 + l15 + dw;
                    af[m] = *reinterpret_cast<const half8*>(
                        &xs[px * 64 + (j ^ (px & 7)) * 8]);
                }
                #pragma unroll
                for (int m = 0; m < 4; m++)
                    #pragma unroll
                    for (int n = 0; n < 3; n++)
                        acc[m][n] = __builtin_amdgcn_mfma_f32_16x16x32_f16(
                            af[m], bf[n], acc[m][n], 0, 0, 0);
            }
    }
    __syncthreads();    // xs/wbuf dead; tb overlays

    // logits (bias added) -> tb [od 0..95][132 px pitch]
    #pragma unroll
    for (int m = 0; m < 4; m++)
        #pragma unroll
        for (int n = 0; n < 3; n++) {
            int od = og * 48 + n * 16 + l15;
            float bv = b_last[ct * 96 + od];
            half4v hv;
            #pragma unroll
            for (int q = 0; q < 4; q++) hv[q] = (_Float16)(acc[m][n][q] + bv);
            *reinterpret_cast<half4v*>(&tb[od * 132 + pxh * 64 + m * 16 + l4 * 4]) = hv;
        }
    __syncthreads();

    // tb -> global, coalesced half8 rows
    _Float16* dst = Lg + (((size_t)bi * 128 + h) * 288 + (size_t)ct * 96) * 128;
    #pragma unroll
    for (int i = 0; i < 6; i++) {
        int id = i * 256 + tid;           // 0..1535
        int od = id >> 4;
        int sl = id & 15;
        half8 v = *reinterpret_cast<const half8*>(&tb[od * 132 + sl * 8]);
        *reinterpret_cast<half8*>(dst + (size_t)od * 128 + sl * 8) = v;
    }
}

// ---------------------------------------------------------------------------
// fuse_sm: barrier-free streaming softmax + combine. One thread per
// output pixel. All loads coalesced; full-occupancy latency hiding.
// ---------------------------------------------------------------------------
__global__ __launch_bounds__(256)
void fuse_sm(const _Float16* __restrict__ Lg, const float* __restrict__ ms,
             const float* __restrict__ zin, float* __restrict__ out, int bbase) {
    int blk = blockIdx.x;
    int bi = blk >> 11;
    int c  = (blk >> 6) & 31;
    int hp = blk & 63;
    int tid = threadIdx.x;
    int h = hp * 2 + (tid >> 7);
    int w = tid & 127;
    int b = bbase + bi;

    const _Float16* lrow = Lg + (((size_t)bi * 128 + h) * 288 + (size_t)c * 9) * 128 + w;
    float L[9];
    float mx = 0.f;                      // implicit zero logit
    #pragma unroll
    for (int j = 0; j < 9; j++) { L[j] = (float)lrow[j * 128]; mx = fmaxf(mx, L[j]); }
    float ez = __expf(-mx);
    float sum = ez;
    float e[9];
    #pragma unroll
    for (int j = 0; j < 9; j++) { e[j] = __expf(L[j] - mx); sum += e[j]; }
    float inv = 1.f / sum;
    const float* msb = ms + ((size_t)b * 32 + c) * IMG;
    float accv = ez * inv * zin[((size_t)b * 32 + c) * IMG + h * HW + w];
    #pragma unroll
    for (int kh = 0; kh < 3; kh++) {
        int h2 = h + kh - 1;
        int h2c = min(max(h2, 0), 127);
        bool okh = (unsigned)h2 < 128u;
        #pragma unroll
        for (int kw = 0; kw < 3; kw++) {
            int w2 = w + kw - 1;
            int w2c = min(max(w2, 0), 127);
            bool okw = (unsigned)w2 < 128u;
            float mv = msb[h2c * HW + w2c];
            accv += e[kh * 3 + kw] * inv * ((okh && okw) ? mv : 0.f);
        }
    }
    out[((size_t)b * 32 + c) * IMG + h * HW + w] = accv;
}

// ---------------------------------------------------------------------------
extern "C" void kernel_launch(void* const* d_in, const int* in_sizes, int n_in,
                              void* d_out, int out_size, void* d_ws, size_t ws_size,
                              hipStream_t stream) {
    const float* z  = (const float*)d_in[0];
    const float* bb = (const float*)d_in[1];
    const float* ms = (const float*)d_in[2];
    const float* mu = (const float*)d_in[3];
    const float* w0 = (const float*)d_in[4];
    const float* b0 = (const float*)d_in[5];
    const float* w1 = (const float*)d_in[6];
    const float* b1 = (const float*)d_in[7];
    const float* w2 = (const float*)d_in[8];
    const float* b2 = (const float*)d_in[9];
    const float* wl = (const float*)d_in[10];
    const float* bl = (const float*)d_in[11];

    char* ws = (char*)d_ws;
    _Float16* Wp0 = (_Float16*)(ws + 0);          // 184320 (fragment-ordered)
    _Float16* Wp1 = (_Float16*)(ws + 184320);     // 73728
    _Float16* Wp2 = (_Float16*)(ws + 258048);     // 73728
    _Float16* WpL = (_Float16*)(ws + 331776);     // 331776
    _Float16* BufA = (_Float16*)(ws + 663552);    // 43,264,000  (160ch padded)
    _Float16* BufB = (_Float16*)(ws + 43927552);  // 17,305,600  (64ch padded)

    _Float16* X0 = BufA;
    _Float16* Q1 = BufB;
    _Float16* Q2 = BufA;   // overlays X0 (dead after conv0)
    _Float16* Q3 = BufB;   // overlays Q1 (same layout -> halo stays zero)
    _Float16* Lg = BufA;   // logits slab (BufA dead after conv2)

    pack_w_all<<<(331776 + 255) / 256, 256, 0, stream>>>(w0, w1, w2, wl, Wp0, Wp1, Wp2, WpL);
    zero_pads_pre<<<(115584 + 255) / 256, 256, 0, stream>>>(X0, Q1);
    pack_in<<<1024, 256, 0, stream>>>(z, bb, ms, mu, X0);

    conv3_c160<<<1024, 256, 0, stream>>>(X0, Wp0, b0, Q1);
    zero_pads64<<<(33024 + 255) / 256, 256, 0, stream>>>(Q2);
    conv3_c64<<<1024, 256, 0, stream>>>(Q1, Wp1, b1, Q2);
    conv3_c64<<<1024, 256, 0, stream>>>(Q2, Wp2, b2, Q3);

    head_gemm<<<1536, 256, 0, stream>>>(Q3, WpL, bl, Lg, 0);
    fuse_sm<<<8192, 256, 0, stream>>>(Lg, ms, z, (float*)d_out, 0);
    head_gemm<<<1536, 256, 0, stream>>>(Q3, WpL, bl, Lg, 4);
    fuse_sm<<<8192, 256, 0, stream>>>(Lg, ms, z, (float*)d_out, 4);
}